// Round 2
// baseline (206.750 us; speedup 1.0000x reference)
//
#include <hip/hip_runtime.h>
#include <cstdint>

// Hierarchical classification head, R10 (= R9 + ancestor-staging bounds fix):
//   cast      : fp32 -> fp8 e4m3 X and W (W pre-scaled x16), bias fp32; also
//               zeroes sum3[4096] and the loss cell (atomics target).
//   gemm_anc  : Zanc = sigmoid((Xq @ Wq[0:640]^T)/16 + b) bf16 [4096][640]
//               (z1 | z2 | z3[0:332)) -- only the ancestor columns persist.
//   gemm3     : fused z3 leaf GEMM, cols [308,3124) of Wq. Epilogue stages
//               14 anc10 + 3 anc100 values/row into LDS (reuses As after
//               last barrier; a 128-col tile spans up to 14 distinct k/10
//               and 3 distinct k/100 -- R9 staged 13/2 and read junk LDS),
//               computes lg = sigmoid(acc/16+b) * anc10 * anc100, writes
//               fp32 out directly, and accumulates per-row sum of exp(lg)
//               via 16-lane shfl_xor + atomicAdd(sum3[row]).
//   ce_kernel : 1 wave/row: s1, s2 from Zanc; l3 = out[b][lab] gather;
//               atomicAdd(loss_cell, partial/4096).
// GEMM core (16B-rotation swizzle, global_load_lds width 16, XCD band
// swizzle, 64x128 tile BK=128) kept verbatim from R8.

typedef unsigned short u16;
typedef unsigned char u8;
typedef long i64;
typedef float f32x4 __attribute__((ext_vector_type(4)));

#define AS_G __attribute__((address_space(1)))
#define AS_L __attribute__((address_space(3)))

constexpr int BATCH = 4096;
constexpr int H     = 1024;
constexpr int N1 = 28, N2 = 280, N3 = 2800;
constexpr int NT = N1 + N2 + N3;   // 3108
constexpr int NP = 3200;           // Wq rows (25 * 128)
constexpr int NANCP = 640;         // Zanc padded cols (combined [0,640))
constexpr int Z3OFF = N1 + N2;     // 308 = start of z3 in combined cols
constexpr float WSCALE = 16.0f;
constexpr float WINV   = 1.0f / 16.0f;

// ancestor staging geometry (gemm3 epilogue)
constexpr int A10  = 14;           // distinct k/10 values per 128-col tile (max)
constexpr int A100 = 3;            // distinct k/100 values per 128-col tile (max)
constexpr int ANC100_BASE = 64 * A10;   // 896 floats

__device__ inline u16 f2bf(float f) {
    unsigned int u = __float_as_uint(f);
    u += 0x7fffu + ((u >> 16) & 1u);
    return (u16)(u >> 16);
}
__device__ inline float bf2f(unsigned int u) { return __uint_as_float(u << 16); }

__device__ inline unsigned int pk4_fp8(float a, float b, float c, float d) {
    unsigned int r = __builtin_amdgcn_cvt_pk_fp8_f32(a, b, 0, false);
    r = __builtin_amdgcn_cvt_pk_fp8_f32(c, d, (int)r, true);
    return r;
}

// ---------------- cast fp32 -> fp8 + fused bias + zero atomics targets ----------------
constexpr int XG = (BATCH * H) / 4;   // 1,048,576
constexpr int WG = (NP * H) / 4;      //   819,200
constexpr int BG = NP / 4;            //       800
constexpr int ZG = BATCH / 4;         //     1,024 (zero sum3)
constexpr int TOTG = XG + WG + BG + ZG;

__global__ __launch_bounds__(256) void cast_kernel(
        const float* __restrict__ x,
        const float* __restrict__ W1, const float* __restrict__ W2,
        const float* __restrict__ W3,
        const float* __restrict__ b1, const float* __restrict__ b2,
        const float* __restrict__ b3,
        u8* __restrict__ Xq, u8* __restrict__ Wq, float* __restrict__ biasf,
        float* __restrict__ sum3, float* __restrict__ loss_cell) {
    int g = blockIdx.x * 256 + threadIdx.x;
    if (g < XG) {
        float4 v = ((const float4*)x)[g];
        ((unsigned int*)Xq)[g] = pk4_fp8(v.x, v.y, v.z, v.w);
    } else if (g < XG + WG) {
        int wg = g - XG;
        int row = wg >> 8, cg = wg & 255;
        float4 v = make_float4(0.f, 0.f, 0.f, 0.f);
        if (row < N1)           v = ((const float4*)W1)[row * 256 + cg];
        else if (row < N1 + N2) v = ((const float4*)W2)[(row - N1) * 256 + cg];
        else if (row < NT)      v = ((const float4*)W3)[(row - N1 - N2) * 256 + cg];
        ((unsigned int*)Wq)[wg] = pk4_fp8(v.x * WSCALE, v.y * WSCALE, v.z * WSCALE, v.w * WSCALE);
    } else if (g < XG + WG + BG) {
        int bg = g - XG - WG;
        float4 v; float* vp = &v.x;
        #pragma unroll
        for (int i = 0; i < 4; ++i) {
            int c = bg * 4 + i; float t = 0.f;
            if (c < N1)           t = b1[c];
            else if (c < N1 + N2) t = b2[c - N1];
            else if (c < NT)      t = b3[c - N1 - N2];
            vp[i] = t;
        }
        ((float4*)biasf)[bg] = v;
    } else if (g < TOTG) {
        int zg = g - XG - WG - BG;
        ((float4*)sum3)[zg] = make_float4(0.f, 0.f, 0.f, 0.f);
        if (zg == 0) *loss_cell = 0.f;
    }
}

// ---------------- GEMM 1: ancestor columns [0,640) -> Zanc bf16 ----------------
// 64x128 tile, BK=128, 4 waves 2x2. Grid 320 (64 m-tiles x 5 n-tiles).
__global__ __launch_bounds__(256) void gemm_anc(
        const u8* __restrict__ Xq, const u8* __restrict__ Wq,
        const float* __restrict__ biasf, u16* __restrict__ Zanc) {
    __shared__ __align__(16) u8 As[4 * 64 * 32];    //  8 KB
    __shared__ __align__(16) u8 Bs[4 * 128 * 32];   // 16 KB

    const int id  = blockIdx.x;        // 0..319
    const int xcd = id & 7;
    const int j   = id >> 3;           // 0..39
    const int m0 = ((xcd << 3) | (j & 7)) * 64;    // m-tile 0..63
    const int n0 = (j >> 3) * 128;                 // n-tile 0..4

    const int tid  = threadIdx.x;
    const int lane = tid & 63;
    const int wave = tid >> 6;
    const int wr = wave >> 1;
    const int wc = wave & 1;

    const int laneM = lane & 15;
    const int u   = lane >> 4;
    const int xb  = (laneM >> 2) & 1;
    const int laneKb = (((u >> 1) ^ xb) << 4) + (u & 1) * 8;

    int arow[2], agoff[2];
    #pragma unroll
    for (int t = 0; t < 2; ++t) {
        const int c = tid + 256 * t;
        const int panel = c >> 7, rem = c & 127;
        const int row = rem >> 1, v = rem & 1;
        arow[t]  = row;
        agoff[t] = panel * 32 + ((v ^ ((row >> 2) & 1)) << 4);
    }
    int brow[4], bgoff[4];
    #pragma unroll
    for (int t = 0; t < 4; ++t) {
        const int c = tid + 256 * t;
        const int panel = c >> 8, rem = c & 255;
        const int row = rem >> 1, v = rem & 1;
        brow[t]  = row;
        bgoff[t] = panel * 32 + ((v ^ ((row >> 2) & 1)) << 4);
    }

    f32x4 acc[2][4] = {};

    for (int kt = 0; kt < H / 128; ++kt) {
        const int k0 = kt * 128;
        #pragma unroll
        for (int t = 0; t < 2; ++t) {
            const int c = tid + 256 * t;
            __builtin_amdgcn_global_load_lds(
                (const AS_G uint32_t*)(Xq + (size_t)(m0 + arow[t]) * H + k0 + agoff[t]),
                (AS_L uint32_t*)&As[c * 16], 16, 0, 0);
        }
        #pragma unroll
        for (int t = 0; t < 4; ++t) {
            const int c = tid + 256 * t;
            __builtin_amdgcn_global_load_lds(
                (const AS_G uint32_t*)(Wq + (size_t)(n0 + brow[t]) * H + k0 + bgoff[t]),
                (AS_L uint32_t*)&Bs[c * 16], 16, 0, 0);
        }
        __syncthreads();

        #pragma unroll
        for (int p = 0; p < 4; ++p) {
            i64 af[2], bfv[4];
            #pragma unroll
            for (int i = 0; i < 2; ++i)
                af[i]  = *(const i64*)&As[p * 2048 + (wr * 32 + i * 16 + laneM) * 32 + laneKb];
            #pragma unroll
            for (int i = 0; i < 4; ++i)
                bfv[i] = *(const i64*)&Bs[p * 4096 + (wc * 64 + i * 16 + laneM) * 32 + laneKb];
            #pragma unroll
            for (int am = 0; am < 2; ++am)
                #pragma unroll
                for (int bn = 0; bn < 4; ++bn)
                    acc[am][bn] = __builtin_amdgcn_mfma_f32_16x16x32_fp8_fp8(
                        af[am], bfv[bn], acc[am][bn], 0, 0, 0);
        }
        __syncthreads();
    }

    #pragma unroll
    for (int bn = 0; bn < 4; ++bn) {
        const int col = n0 + wc * 64 + bn * 16 + laneM;   // < 640 always
        const float bias = biasf[col];
        #pragma unroll
        for (int am = 0; am < 2; ++am) {
            const int rbase = m0 + wr * 32 + am * 16 + (lane >> 4) * 4;
            #pragma unroll
            for (int r = 0; r < 4; ++r) {
                float v = acc[am][bn][r] * WINV + bias;
                Zanc[(size_t)(rbase + r) * NANCP + col] = f2bf(1.0f / (1.0f + __expf(-v)));
            }
        }
    }
}

// ---------------- GEMM 2: z3 leaf columns, fused logits + sumexp ----------------
// cols (z3 space) [0,2816) in 22 n-tiles of 128; Wq rows Z3OFF+c.
// Grid 1408 (64 m-tiles x 22 n-tiles).
__global__ __launch_bounds__(256) void gemm3(
        const u8* __restrict__ Xq, const u8* __restrict__ Wq,
        const float* __restrict__ biasf, const u16* __restrict__ Zanc,
        float* __restrict__ out, float* __restrict__ sum3) {
    __shared__ __align__(16) u8 As[4 * 64 * 32];    //  8 KB
    __shared__ __align__(16) u8 Bs[4 * 128 * 32];   // 16 KB

    const int id  = blockIdx.x;        // 0..1407
    const int xcd = id & 7;
    const int j   = id >> 3;           // 0..175
    const int m0 = ((xcd << 3) | (j & 7)) * 64;    // m-tile 0..63
    const int c0 = (j >> 3) * 128;                 // z3 col base, n-tile 0..21

    const int tid  = threadIdx.x;
    const int lane = tid & 63;
    const int wave = tid >> 6;
    const int wr = wave >> 1;
    const int wc = wave & 1;

    const int laneM = lane & 15;
    const int u   = lane >> 4;
    const int xb  = (laneM >> 2) & 1;
    const int laneKb = (((u >> 1) ^ xb) << 4) + (u & 1) * 8;

    int arow[2], agoff[2];
    #pragma unroll
    for (int t = 0; t < 2; ++t) {
        const int c = tid + 256 * t;
        const int panel = c >> 7, rem = c & 127;
        const int row = rem >> 1, v = rem & 1;
        arow[t]  = row;
        agoff[t] = panel * 32 + ((v ^ ((row >> 2) & 1)) << 4);
    }
    int brow[4], bgoff[4];
    #pragma unroll
    for (int t = 0; t < 4; ++t) {
        const int c = tid + 256 * t;
        const int panel = c >> 8, rem = c & 255;
        const int row = rem >> 1, v = rem & 1;
        brow[t]  = row;
        bgoff[t] = panel * 32 + ((v ^ ((row >> 2) & 1)) << 4);
    }

    f32x4 acc[2][4] = {};

    for (int kt = 0; kt < H / 128; ++kt) {
        const int k0 = kt * 128;
        #pragma unroll
        for (int t = 0; t < 2; ++t) {
            const int c = tid + 256 * t;
            __builtin_amdgcn_global_load_lds(
                (const AS_G uint32_t*)(Xq + (size_t)(m0 + arow[t]) * H + k0 + agoff[t]),
                (AS_L uint32_t*)&As[c * 16], 16, 0, 0);
        }
        #pragma unroll
        for (int t = 0; t < 4; ++t) {
            const int c = tid + 256 * t;
            __builtin_amdgcn_global_load_lds(
                (const AS_G uint32_t*)(Wq + (size_t)(Z3OFF + c0 + brow[t]) * H + k0 + bgoff[t]),
                (AS_L uint32_t*)&Bs[c * 16], 16, 0, 0);
        }
        __syncthreads();

        #pragma unroll
        for (int p = 0; p < 4; ++p) {
            i64 af[2], bfv[4];
            #pragma unroll
            for (int i = 0; i < 2; ++i)
                af[i]  = *(const i64*)&As[p * 2048 + (wr * 32 + i * 16 + laneM) * 32 + laneKb];
            #pragma unroll
            for (int i = 0; i < 4; ++i)
                bfv[i] = *(const i64*)&Bs[p * 4096 + (wc * 64 + i * 16 + laneM) * 32 + laneKb];
            #pragma unroll
            for (int am = 0; am < 2; ++am)
                #pragma unroll
                for (int bn = 0; bn < 4; ++bn)
                    acc[am][bn] = __builtin_amdgcn_mfma_f32_16x16x32_fp8_fp8(
                        af[am], bfv[bn], acc[am][bn], 0, 0, 0);
        }
        __syncthreads();
    }

    // --- stage the block's ancestor values into LDS (reuse As: all reads done) ---
    // anc10 : z3anc[k/10]  for k in [c0, c0+128) -> up to 14 values per row
    // anc100: z3anc[k/100]                       -> up to  3 values per row
    // (A 128-col tile spans floor((c0+127)/10)-floor(c0/10) <= 13 extra
    //  k/10 slots and up to 2 extra k/100 slots; 14/3 covers all c0.)
    float* ancs = (float*)As;     // 64*14 + 64*3 = 1088 floats = 4352 B < 8 KB
    const int j10  = c0 / 10;
    const int j100 = c0 / 100;
    for (int i = tid; i < 64 * A10; i += 256) {
        int row = i / A10, jj = i - row * A10;
        ancs[i] = bf2f((unsigned int)Zanc[(size_t)(m0 + row) * NANCP + Z3OFF + j10 + jj]);
    }
    if (tid < 64 * A100) {
        int row = tid / A100, jj = tid - row * A100;
        ancs[ANC100_BASE + tid] =
            bf2f((unsigned int)Zanc[(size_t)(m0 + row) * NANCP + Z3OFF + j100 + jj]);
    }
    __syncthreads();

    // --- fused epilogue: lg = sigmoid(acc/16+b)*anc10*anc100, write fp32,
    //     accumulate exp(lg) per row ---
    float sume[2][4] = {};   // [am][r]
    #pragma unroll
    for (int bn = 0; bn < 4; ++bn) {
        const int colg = wc * 64 + bn * 16 + laneM;
        const int k = c0 + colg;                 // z3 col
        const bool ok = k < N3;
        const float bias = biasf[Z3OFF + k];
        const int d10  = k / 10  - j10;          // in [0,13]
        const int d100 = k / 100 - j100;         // in [0,2]
        #pragma unroll
        for (int am = 0; am < 2; ++am) {
            const int rb = wr * 32 + am * 16 + u * 4;   // row in tile
            #pragma unroll
            for (int r = 0; r < 4; ++r) {
                const int row = rb + r;
                float v = acc[am][bn][r] * WINV + bias;
                float z = 1.0f / (1.0f + __expf(-v));
                float lg = z * ancs[row * A10 + d10] * ancs[ANC100_BASE + row * A100 + d100];
                if (ok) {
                    out[(size_t)(m0 + row) * N3 + k] = lg;
                    sume[am][r] += __expf(lg);
                }
            }
        }
    }
    #pragma unroll
    for (int am = 0; am < 2; ++am)
        #pragma unroll
        for (int r = 0; r < 4; ++r) {
            float s = sume[am][r];
            s += __shfl_xor(s, 1, 64);
            s += __shfl_xor(s, 2, 64);
            s += __shfl_xor(s, 4, 64);
            s += __shfl_xor(s, 8, 64);
            if (laneM == 0)
                atomicAdd(&sum3[m0 + wr * 32 + am * 16 + u * 4 + r], s);
        }
}

// ---------------- CE: one wave per row; fused final reduce via atomic ----------------
__global__ __launch_bounds__(256) void ce_kernel(
        const u16* __restrict__ Zanc, const float* __restrict__ out,
        const int* __restrict__ labels, const float* __restrict__ sum3,
        float* __restrict__ loss_cell) {
    const int tid  = threadIdx.x;
    const int lane = tid & 63;
    const int b    = blockIdx.x * 4 + (tid >> 6);
    const u16* Zr = Zanc + (size_t)b * NANCP;

    float s1 = (lane < N1) ? __expf(bf2f((unsigned int)Zr[lane])) : 0.f;
    float s2 = 0.f;
    for (int jj = lane; jj < N2; jj += 64)
        s2 += __expf(bf2f((unsigned int)Zr[N1 + jj]) * bf2f((unsigned int)Zr[N1 + jj / 10]));
    #pragma unroll
    for (int off = 32; off > 0; off >>= 1) {
        s1 += __shfl_down(s1, off, 64);
        s2 += __shfl_down(s2, off, 64);
    }
    if (lane == 0) {
        const int lab  = labels[b];
        const int lab2 = lab / 10, lab1 = lab / 100;
        const float l1 = bf2f((unsigned int)Zr[lab1]);
        const float l2 = bf2f((unsigned int)Zr[N1 + lab2]) * bf2f((unsigned int)Zr[N1 + lab2 / 10]);
        const float l3 = out[(size_t)b * N3 + lab];
        const float s3 = sum3[b];
        const float partial = (logf(s1) - l1) + (logf(s2) - l2) + (logf(s3) - l3);
        atomicAdd(loss_cell, partial * (1.0f / BATCH));
    }
}

extern "C" void kernel_launch(void* const* d_in, const int* in_sizes, int n_in,
                              void* d_out, int out_size, void* d_ws, size_t ws_size,
                              hipStream_t stream) {
    const float* x      = (const float*)d_in[0];
    const int*   labels = (const int*)d_in[1];
    const float* W1     = (const float*)d_in[2];
    const float* b1     = (const float*)d_in[3];
    const float* W2     = (const float*)d_in[4];
    const float* b2     = (const float*)d_in[5];
    const float* W3     = (const float*)d_in[6];
    const float* b3     = (const float*)d_in[7];
    float* out = (float*)d_out;

    char* ws = (char*)d_ws;
    u8*    Xq    = (u8*)ws;                    //  4,194,304 B  [4096][1024] fp8
    u8*    Wq    = (u8*)(ws + 4194304);        //  3,276,800 B  [3200][1024] fp8
    u16*   Zanc  = (u16*)(ws + 7471104);       //  5,242,880 B  [4096][640] bf16
    float* biasf = (float*)(ws + 12713984);    //     12,800 B
    float* sum3  = (float*)(ws + 12726784);    //     16,384 B
    // total ws use: 12,743,168 B
    float* loss_cell = out + (size_t)BATCH * N3;

    cast_kernel<<<(TOTG + 255) / 256, 256, 0, stream>>>(
        x, W1, W2, W3, b1, b2, b3, Xq, Wq, biasf, sum3, loss_cell);
    gemm_anc<<<320, 256, 0, stream>>>(Xq, Wq, biasf, Zanc);
    gemm3<<<1408, 256, 0, stream>>>(Xq, Wq, biasf, Zanc, out, sum3);
    ce_kernel<<<BATCH / 4, 256, 0, stream>>>(Zanc, out, labels, sum3, loss_cell);
}

// Round 3
// 149.364 us; speedup vs baseline: 1.3842x; 1.3842x over previous
//
#include <hip/hip_runtime.h>
#include <cstdint>

// Hierarchical classification head, R11 (= R8 structure + pipelined GEMM):
//   cast         : fp32 -> fp8 e4m3 X and W (W pre-scaled x16), bias fp32
//   gemm_sig     : Zb = sigmoid((Xq @ Wq^T)/16 + b) bf16; fp8 MFMA 16x16x32.
//                  NEW (R11): BK=64 double-buffered prefetch (T3 minimum
//                  2-phase): STAGE(buf^1, kt+1) issued BEFORE compute(buf),
//                  one barrier/iter -> loads overlap MFMA instead of the R8
//                  drain-before-compute. LDS stays 24 KB (6 blocks/CU).
//                  16B-rotation LDS swizzle (R7) + XCD band swizzle (R4) +
//                  64x128 tile, 1600 blocks (R8) kept verbatim.
//   logits_loss  : per-row logits3 -> d_out; ONLY 588 ancestor z in LDS,
//                  z3[k] streamed from global (R8, measured good)
//   final_reduce : 4096 partials -> mean loss scalar (no global atomics --
//                  R10's single-cell atomicAdd was a suspected regression)

typedef unsigned short u16;
typedef unsigned char u8;
typedef long i64;
typedef float f32x4 __attribute__((ext_vector_type(4)));

#define AS_G __attribute__((address_space(1)))
#define AS_L __attribute__((address_space(3)))

constexpr int BATCH = 4096;
constexpr int H     = 1024;
constexpr int N1 = 28, N2 = 280, N3 = 2800;
constexpr int NT = N1 + N2 + N3;   // 3108
constexpr int NP = 3200;           // 25 * 128
constexpr int NANC = N1 + N2 + 280;  // 588 ancestor values
constexpr float WSCALE = 16.0f;
constexpr float WINV   = 1.0f / 16.0f;

__device__ inline u16 f2bf(float f) {
    unsigned int u = __float_as_uint(f);
    u += 0x7fffu + ((u >> 16) & 1u);
    return (u16)(u >> 16);
}
__device__ inline float bf2f(unsigned int u) { return __uint_as_float(u << 16); }

__device__ inline unsigned int pk4_fp8(float a, float b, float c, float d) {
    unsigned int r = __builtin_amdgcn_cvt_pk_fp8_f32(a, b, 0, false);
    r = __builtin_amdgcn_cvt_pk_fp8_f32(c, d, (int)r, true);
    return r;
}

// ---------------- cast fp32 -> fp8 + fused bias ----------------
constexpr int XG = (BATCH * H) / 4;   // 1,048,576
constexpr int WG = (NP * H) / 4;      //   819,200
constexpr int BG = NP / 4;            //       800

__global__ __launch_bounds__(256) void cast_kernel(
        const float* __restrict__ x,
        const float* __restrict__ W1, const float* __restrict__ W2,
        const float* __restrict__ W3,
        const float* __restrict__ b1, const float* __restrict__ b2,
        const float* __restrict__ b3,
        u8* __restrict__ Xq, u8* __restrict__ Wq, float* __restrict__ biasf) {
    int g = blockIdx.x * 256 + threadIdx.x;
    if (g < XG) {
        float4 v = ((const float4*)x)[g];
        ((unsigned int*)Xq)[g] = pk4_fp8(v.x, v.y, v.z, v.w);
    } else if (g < XG + WG) {
        int wg = g - XG;
        int row = wg >> 8, cg = wg & 255;
        float4 v = make_float4(0.f, 0.f, 0.f, 0.f);
        if (row < N1)           v = ((const float4*)W1)[row * 256 + cg];
        else if (row < N1 + N2) v = ((const float4*)W2)[(row - N1) * 256 + cg];
        else if (row < NT)      v = ((const float4*)W3)[(row - N1 - N2) * 256 + cg];
        ((unsigned int*)Wq)[wg] = pk4_fp8(v.x * WSCALE, v.y * WSCALE, v.z * WSCALE, v.w * WSCALE);
    } else if (g < XG + WG + BG) {
        int bg = g - XG - WG;
        float4 v; float* vp = &v.x;
        #pragma unroll
        for (int i = 0; i < 4; ++i) {
            int c = bg * 4 + i; float t = 0.f;
            if (c < N1)           t = b1[c];
            else if (c < N1 + N2) t = b2[c - N1];
            else if (c < NT)      t = b3[c - N1 - N2];
            vp[i] = t;
        }
        ((float4*)biasf)[bg] = v;
    }
}

// ---------------- GEMM: Zb = sigmoid(acc/16 + bias), fp8 inputs, bf16 out ----------------
// 64x128 tile, BK=64, double-buffered prefetch, 16 iters, 4 waves 2x2.
// LDS 2*(4+8) KB = 24 KB -> 6 blocks/CU resource-fit (same as R8).
__global__ __launch_bounds__(256) void gemm_sig(
        const u8* __restrict__ Xq, const u8* __restrict__ Wq,
        const float* __restrict__ biasf, u16* __restrict__ Zb) {
    __shared__ __align__(16) u8 As[2][2 * 64 * 32];    // 4 KB per buffer
    __shared__ __align__(16) u8 Bs[2][2 * 128 * 32];   // 8 KB per buffer

    // XCD band swizzle: 64 m-tiles x 25 n-tiles; XCD owns 8-m-tile band.
    const int id  = blockIdx.x;        // 0..1599
    const int xcd = id & 7;
    const int j   = id >> 3;           // 0..199
    const int m0 = ((xcd << 3) | (j & 7)) * 64;    // m-tile 0..63
    const int n0 = (j >> 3) * 128;                 // n-tile 0..24

    const int tid  = threadIdx.x;
    const int lane = tid & 63;
    const int wave = tid >> 6;
    const int wr = wave >> 1;          // m half (32 rows)
    const int wc = wave & 1;           // n half (64 cols)

    const int laneM = lane & 15;
    // 16B-rotation swizzle (R7): unit index = (u>>1) ^ ((row>>2)&1)
    const int u   = lane >> 4;
    const int xb  = (laneM >> 2) & 1;
    const int laneKb = (((u >> 1) ^ xb) << 4) + (u & 1) * 8;

    // A staging: 256 chunks (16B), 1/thread. chunk c: panel=c>>7, rem=c&127,
    // row=rem>>1, v=rem&1.
    const int ac = tid;
    const int apanel = ac >> 7, arem = ac & 127;
    const int arowi = arem >> 1, av = arem & 1;
    const int agoff = apanel * 32 + ((av ^ ((arowi >> 2) & 1)) << 4);
    // B staging: 512 chunks, 2/thread.
    int brow[2], bgoff[2];
    #pragma unroll
    for (int t = 0; t < 2; ++t) {
        const int c = tid + 256 * t;
        const int panel = c >> 8, rem = c & 255;
        const int row = rem >> 1, v = rem & 1;
        brow[t]  = row;
        bgoff[t] = panel * 32 + ((v ^ ((row >> 2) & 1)) << 4);
    }

    auto STAGE = [&](int bufi, int kt) {
        const int k0 = kt * 64;
        __builtin_amdgcn_global_load_lds(
            (const AS_G uint32_t*)(Xq + (size_t)(m0 + arowi) * H + k0 + agoff),
            (AS_L uint32_t*)&As[bufi][ac * 16], 16, 0, 0);
        #pragma unroll
        for (int t = 0; t < 2; ++t) {
            const int c = tid + 256 * t;
            __builtin_amdgcn_global_load_lds(
                (const AS_G uint32_t*)(Wq + (size_t)(n0 + brow[t]) * H + k0 + bgoff[t]),
                (AS_L uint32_t*)&Bs[bufi][c * 16], 16, 0, 0);
        }
    };

    f32x4 acc[2][4] = {};

    STAGE(0, 0);
    __syncthreads();                   // drains vmcnt(0): buf 0 ready
    int buf = 0;
    for (int kt = 0; kt < H / 64; ++kt) {          // 16 iterations
        if (kt + 1 < H / 64) STAGE(buf ^ 1, kt + 1);   // loads fly under compute
        #pragma unroll
        for (int p = 0; p < 2; ++p) {               // 2 k-panels of 32
            i64 af[2], bfv[4];
            #pragma unroll
            for (int i = 0; i < 2; ++i)
                af[i]  = *(const i64*)&As[buf][p * 2048 + (wr * 32 + i * 16 + laneM) * 32 + laneKb];
            #pragma unroll
            for (int i = 0; i < 4; ++i)
                bfv[i] = *(const i64*)&Bs[buf][p * 4096 + (wc * 64 + i * 16 + laneM) * 32 + laneKb];
            #pragma unroll
            for (int am = 0; am < 2; ++am)
                #pragma unroll
                for (int bn = 0; bn < 4; ++bn)
                    acc[am][bn] = __builtin_amdgcn_mfma_f32_16x16x32_fp8_fp8(
                        af[am], bfv[bn], acc[am][bn], 0, 0, 0);
        }
        __syncthreads();               // next buffer's loads landed; reads done
        buf ^= 1;
    }

    // epilogue: C/D layout col = lane&15, row = (lane>>4)*4 + r; unscale, bf16 store
    #pragma unroll
    for (int bn = 0; bn < 4; ++bn) {
        const int col = n0 + wc * 64 + bn * 16 + laneM;
        if (col >= NT) continue;
        const float bias = biasf[col];
        #pragma unroll
        for (int am = 0; am < 2; ++am) {
            const int rbase = m0 + wr * 32 + am * 16 + (lane >> 4) * 4;
            #pragma unroll
            for (int r = 0; r < 4; ++r) {
                float v = acc[am][bn][r] * WINV + bias;
                Zb[(size_t)(rbase + r) * NP + col] = f2bf(1.0f / (1.0f + __expf(-v)));
            }
        }
    }
}

// ---------------- per-row logits + CE partial (no atomic) ----------------
// LDS holds only the 588 ancestor z (z1|z2|z3[0:280)); z3[k] streamed global.
__global__ __launch_bounds__(256) void logits_loss(
        const u16* __restrict__ Zb, const int* __restrict__ labels,
        float* __restrict__ out, float* __restrict__ partials) {
    __shared__ float zs[NANC];             // [0,28) z1 | [28,308) z2 | [308,588) z3[0:280)
    __shared__ float red[12];
    const int b = blockIdx.x, tid = threadIdx.x;
    const u16* Zrow = Zb + (size_t)b * NP;

    const unsigned int* Zr = (const unsigned int*)Zrow;
    for (int i = tid; i < NANC / 2; i += 256) {    // 294 uints
        unsigned int v = Zr[i];
        zs[2 * i]     = bf2f(v & 0xffffu);
        zs[2 * i + 1] = bf2f(v >> 16);
    }
    __syncthreads();

    float se1 = 0.f, se2 = 0.f, se3 = 0.f;
    float4* outr4 = (float4*)(out + (size_t)b * N3);
    // z3 block starts at element 308 (uint index 154, even -> uint2-aligned)
    const uint2* Z3s = (const uint2*)(Zrow + N1 + N2);
    for (int q = tid; q < N3 / 4; q += 256) {
        const uint2 zv = Z3s[q];               // z3[4q..4q+3]
        float z3v[4] = { bf2f(zv.x & 0xffffu), bf2f(zv.x >> 16),
                         bf2f(zv.y & 0xffffu), bf2f(zv.y >> 16) };
        const int k = q * 4;
        float4 o; float* op = &o.x;
        #pragma unroll
        for (int uu = 0; uu < 4; ++uu) {
            const int kk = k + uu;
            float lg = z3v[uu] * zs[308 + kk / 10] * zs[308 + kk / 100];
            op[uu] = lg;
            se3 += __expf(lg);
        }
        outr4[q] = o;
    }
    for (int jj = tid; jj < N2; jj += 256)
        se2 += __expf(zs[N1 + jj] * zs[N1 + jj / 10]);
    if (tid < N1)
        se1 = __expf(zs[tid]);

    #pragma unroll
    for (int off = 32; off > 0; off >>= 1) {
        se1 += __shfl_down(se1, off, 64);
        se2 += __shfl_down(se2, off, 64);
        se3 += __shfl_down(se3, off, 64);
    }
    if ((tid & 63) == 0) {
        int w = tid >> 6;
        red[w] = se3; red[4 + w] = se2; red[8 + w] = se1;
    }
    __syncthreads();
    if (tid == 0) {
        float s3 = red[0] + red[1] + red[2] + red[3];
        float s2 = red[4] + red[5] + red[6] + red[7];
        float s1 = red[8] + red[9] + red[10] + red[11];
        int lab  = labels[b];
        int lab2 = lab / 10, lab1 = lab / 100;
        float l1 = zs[lab1];
        float l2 = zs[N1 + lab2] * zs[N1 + lab2 / 10];
        float l3 = bf2f((unsigned int)Zrow[N1 + N2 + lab]) * zs[308 + lab2] * zs[308 + lab1];
        partials[b] = (logf(s1) - l1) + (logf(s2) - l2) + (logf(s3) - l3);
    }
}

// ---------------- final loss reduce ----------------
__global__ __launch_bounds__(256) void final_reduce(
        const float* __restrict__ partials, float* __restrict__ out) {
    __shared__ float red[4];
    const int tid = threadIdx.x;
    float s = 0.f;
    for (int i = tid; i < BATCH; i += 256) s += partials[i];
    #pragma unroll
    for (int off = 32; off > 0; off >>= 1) s += __shfl_down(s, off, 64);
    if ((tid & 63) == 0) red[tid >> 6] = s;
    __syncthreads();
    if (tid == 0)
        out[(size_t)BATCH * N3] = (red[0] + red[1] + red[2] + red[3]) * (1.0f / BATCH);
}

extern "C" void kernel_launch(void* const* d_in, const int* in_sizes, int n_in,
                              void* d_out, int out_size, void* d_ws, size_t ws_size,
                              hipStream_t stream) {
    const float* x      = (const float*)d_in[0];
    const int*   labels = (const int*)d_in[1];
    const float* W1     = (const float*)d_in[2];
    const float* b1     = (const float*)d_in[3];
    const float* W2     = (const float*)d_in[4];
    const float* b2     = (const float*)d_in[5];
    const float* W3     = (const float*)d_in[6];
    const float* b3     = (const float*)d_in[7];
    float* out = (float*)d_out;

    char* ws = (char*)d_ws;
    u8*    Xq       = (u8*)ws;                     //  4,194,304 B  [4096][1024] fp8
    u8*    Wq       = (u8*)(ws + 4194304);         //  3,276,800 B  [3200][1024] fp8
    u16*   Zb       = (u16*)(ws + 7471104);        // 26,214,400 B  [4096][3200] bf16
    float* biasf    = (float*)(ws + 33685504);     //     12,800 B
    float* partials = (float*)(ws + 33698304);     //     16,384 B
    // total ws use: 33,714,688 B

    cast_kernel<<<(XG + WG + BG + 255) / 256, 256, 0, stream>>>(
        x, W1, W2, W3, b1, b2, b3, Xq, Wq, biasf);
    gemm_sig<<<1600, 256, 0, stream>>>(Xq, Wq, biasf, Zb);
    logits_loss<<<BATCH, 256, 0, stream>>>(Zb, labels, out, partials);
    final_reduce<<<1, 256, 0, stream>>>(partials, out);
}